// Round 12
// baseline (135.575 us; speedup 1.0000x reference)
//
#include <hip/hip_runtime.h>
#include <math.h>

// MultiheadSelfAttention2D: C=256, AC=64, HEADS=16, HEAD_DIM=4, L=4096.
// Taylor-linearized attention (R5): exp(q.k) ~= T5 on [-1,1], exact rank-126
// monomial factorization:
//   S_f = (1/a!) sum_m k_m^a ;  Z_j = sum_f q_j^a S_f
//   M[f][d] = (1/a!) sum_j q_j^a V[d,j]/Z_j ;  out[d,i] = sum_f k_i^a M[f][d]
//
// R12: 4 dispatches. R11 proved coop grid.sync ~= dispatch boundary (neutral),
// so the lever is fewer boundaries + less work: zvz merged INTO mmat (zmv):
// each (fc,h,jc) block folds Sp->Sf in 512B LDS and recomputes Z_j inline
// (monomials already computed for M-accum; Sf reads vectorize to
// ds_read_b128). Kills one dispatch + the Vz 2MB round-trip.
// Chain: qkv | ssum | zmv | outfuse.

constexpr int SL = 4096;
constexpr int NF = 126;

__device__ __forceinline__ float invfact(int e) {
    return e < 2 ? 1.f : e == 2 ? 0.5f : e == 3 ? (1.f / 6.f)
         : e == 4 ? (1.f / 24.f) : (1.f / 120.f);
}
__device__ __forceinline__ void f2abcd(int f, int& A, int& B, int& C, int& D) {
    for (int a = 0; a <= 5; ++a)
        for (int b = 0; b <= 5 - a; ++b)
            for (int c = 0; c <= 5 - a - b; ++c)
                for (int d = 0; d <= 5 - a - b - c; ++d)
                    if (f-- == 0) { A = a; B = b; C = c; D = d; return; }
}

#define FOR_MONOMIALS(BODY)                         \
    {                                               \
        int f = 0;                                  \
        _Pragma("unroll")                           \
        for (int a = 0; a <= 5; ++a)                \
        _Pragma("unroll")                           \
        for (int b = 0; b <= 5 - a; ++b)            \
        _Pragma("unroll")                           \
        for (int c = 0; c <= 5 - a - b; ++c)        \
        _Pragma("unroll")                           \
        for (int d = 0; d <= 5 - a - b - c; ++d) {  \
            BODY;                                   \
            ++f;                                    \
        }                                           \
    }

#define BUILD_POWERS(q)                                   \
    float p0[6], p1[6], p2[6], p3[6];                     \
    p0[0] = p1[0] = p2[0] = p3[0] = 1.f;                  \
    _Pragma("unroll")                                     \
    for (int t_ = 1; t_ < 6; ++t_) {                      \
        p0[t_] = p0[t_ - 1] * (q).x; p1[t_] = p1[t_ - 1] * (q).y; \
        p2[t_] = p2[t_ - 1] * (q).z; p3[t_] = p3[t_ - 1] * (q).w; }

// ---------------------------------------------------------------------------
// Kernel 1: QKV projection + L2-norm. Grid (64 l-tiles, 12 row-blocks),
// block 256 (4 waves x 4 rows). No LDS: X streamed via L1/L2.
// ---------------------------------------------------------------------------
__global__ __launch_bounds__(256) void qkv_kernel(
    const float* __restrict__ X,
    const float* __restrict__ Wq, const float* __restrict__ bq,
    const float* __restrict__ Wk, const float* __restrict__ bk,
    const float* __restrict__ Wv, const float* __restrict__ bv,
    float* __restrict__ Qn, float* __restrict__ Kn, float* __restrict__ V4)
{
    const int tid  = threadIdx.x;
    const int lane = tid & 63;
    const int wv   = __builtin_amdgcn_readfirstlane(tid >> 6);
    const int lt   = blockIdx.x;
    const int rb   = blockIdx.y;               // 12 blocks of 16 rows
    const int type = rb >> 2;                  // 0=Q 1=K 2=V, block-uniform
    const int rit  = (rb & 3) * 16 + wv * 4;   // row-in-type, wave-uniform
    const int l    = lt * 64 + lane;

    const float* W = type == 0 ? Wq : type == 1 ? Wk : Wv;
    const float* B = type == 0 ? bq : type == 1 ? bk : bv;
    const float* w0 = W + (rit + 0) * 256;
    const float* w1 = W + (rit + 1) * 256;
    const float* w2 = W + (rit + 2) * 256;
    const float* w3 = W + (rit + 3) * 256;

    float y0 = B[rit + 0], y1 = B[rit + 1], y2 = B[rit + 2], y3 = B[rit + 3];
    const float* Xl = X + l;
    #pragma unroll 8
    for (int c = 0; c < 256; ++c) {
        float x = Xl[c * SL];
        y0 = fmaf(w0[c], x, y0);
        y1 = fmaf(w1[c], x, y1);
        y2 = fmaf(w2[c], x, y2);
        y3 = fmaf(w3[c], x, y3);
    }
    if (type < 2) {
        float n = sqrtf(y0*y0 + y1*y1 + y2*y2 + y3*y3);
        float inv = 1.f / fmaxf(n, 1e-12f);
        y0 *= inv; y1 *= inv; y2 *= inv; y3 *= inv;
    }
    const int h = rit >> 2;
    float* base = type == 0 ? Qn : type == 1 ? Kn : V4;
    ((float4*)base)[h * SL + l] = make_float4(y0, y1, y2, y3);
}

// ---------------------------------------------------------------------------
// Kernel 2: Sp[jc][h][f] = (1/a!) sum over j-chunk(1024) of k^a.
// Grid (16 f-chunks, 16 h, 4 jc) = 1024 blocks.
// ---------------------------------------------------------------------------
template <int FC>
__device__ __forceinline__ void psi_accum(int h, int jc, int tid,
        const float* __restrict__ Kn, float acc[8])
{
    for (int u = 0; u < 4; ++u) {
        int j = jc * 1024 + u * 256 + tid;
        float4 k = ((const float4*)Kn)[h * SL + j];
        BUILD_POWERS(k)
        FOR_MONOMIALS({
            if (f >= FC * 8 && f < FC * 8 + 8)
                acc[f - FC * 8] += (p0[a] * p1[b]) * (p2[c] * p3[d]);
        })
    }
}

__global__ __launch_bounds__(256) void ssum_kernel(
    const float* __restrict__ Kn, float* __restrict__ Sp)
{
    const int tid = threadIdx.x;
    const int fc  = blockIdx.x;
    const int h   = blockIdx.y;
    const int jc  = blockIdx.z;
    float acc[8];
    #pragma unroll
    for (int k = 0; k < 8; ++k) acc[k] = 0.f;
    switch (fc) {
        case 0:  psi_accum<0 >(h, jc, tid, Kn, acc); break;
        case 1:  psi_accum<1 >(h, jc, tid, Kn, acc); break;
        case 2:  psi_accum<2 >(h, jc, tid, Kn, acc); break;
        case 3:  psi_accum<3 >(h, jc, tid, Kn, acc); break;
        case 4:  psi_accum<4 >(h, jc, tid, Kn, acc); break;
        case 5:  psi_accum<5 >(h, jc, tid, Kn, acc); break;
        case 6:  psi_accum<6 >(h, jc, tid, Kn, acc); break;
        case 7:  psi_accum<7 >(h, jc, tid, Kn, acc); break;
        case 8:  psi_accum<8 >(h, jc, tid, Kn, acc); break;
        case 9:  psi_accum<9 >(h, jc, tid, Kn, acc); break;
        case 10: psi_accum<10>(h, jc, tid, Kn, acc); break;
        case 11: psi_accum<11>(h, jc, tid, Kn, acc); break;
        case 12: psi_accum<12>(h, jc, tid, Kn, acc); break;
        case 13: psi_accum<13>(h, jc, tid, Kn, acc); break;
        case 14: psi_accum<14>(h, jc, tid, Kn, acc); break;
        default: psi_accum<15>(h, jc, tid, Kn, acc); break;
    }
    #pragma unroll
    for (int off = 32; off; off >>= 1)
        #pragma unroll
        for (int k = 0; k < 8; ++k) acc[k] += __shfl_down(acc[k], off);
    __shared__ float red[4][8];
    const int lane = tid & 63, wv = tid >> 6;
    if (lane == 0) {
        #pragma unroll
        for (int k = 0; k < 8; ++k) red[wv][k] = acc[k];
    }
    __syncthreads();
    if (tid < 8) {
        int f = fc * 8 + tid;
        if (f < NF) {
            float s = (red[0][tid] + red[1][tid]) + (red[2][tid] + red[3][tid]);
            int A, B, C, D; f2abcd(f, A, B, C, D);
            Sp[(jc * 16 + h) * 128 + f] =
                s * ((invfact(A) * invfact(B)) * (invfact(C) * invfact(D)));
        }
    }
}

// ---------------------------------------------------------------------------
// Kernel 3 (zmv): fold Sp->Sf (LDS, 512B); per j: Z inline (monomials reused),
// vz = V/Z; accumulate 16 features x 4 d. Grid (8 fc16, 16 h, 4 jc) = 512.
// ---------------------------------------------------------------------------
template <int FC>
__device__ __forceinline__ void zm_accum(int h, int jc, int tid,
        const float* __restrict__ Qn, const float* __restrict__ V4,
        const float* __restrict__ Sf, float acc[64])
{
    for (int u = 0; u < 4; ++u) {
        int j = jc * 1024 + u * 256 + tid;
        float4 q = ((const float4*)Qn)[h * SL + j];
        BUILD_POWERS(q)
        float z = 0.f;
        float mchunk[16];
        FOR_MONOMIALS({
            float mono = (p0[a] * p1[b]) * (p2[c] * p3[d]);
            z = fmaf(mono, Sf[f], z);          // Sf: LDS, vectorizes b128
            if (f >= FC * 16 && f < FC * 16 + 16) mchunk[f - FC * 16] = mono;
        })
        float inv = 1.f / z;
        float4 v = ((const float4*)V4)[h * SL + j];
        float vx = v.x * inv, vy = v.y * inv, vz_ = v.z * inv, vw = v.w * inv;
        #pragma unroll
        for (int fi = 0; fi < 16; ++fi) {
            float m = mchunk[fi];
            acc[fi*4+0] = fmaf(m, vx,  acc[fi*4+0]);
            acc[fi*4+1] = fmaf(m, vy,  acc[fi*4+1]);
            acc[fi*4+2] = fmaf(m, vz_, acc[fi*4+2]);
            acc[fi*4+3] = fmaf(m, vw,  acc[fi*4+3]);
        }
    }
}

__global__ __launch_bounds__(256) void zmv_kernel(
    const float* __restrict__ Qn, const float* __restrict__ V4,
    const float* __restrict__ Sp, float* __restrict__ Mp)
{
    __shared__ float Sf[128];
    __shared__ float red[4][64];
    const int tid = threadIdx.x;
    const int fc  = blockIdx.x;                // 8 chunks of 16 features
    const int h   = blockIdx.y;
    const int jc  = blockIdx.z;

    if (tid < 128) {
        float s = 0.f;
        #pragma unroll
        for (int p = 0; p < 4; ++p) s += Sp[(p * 16 + h) * 128 + tid];
        Sf[tid] = s;
    }
    __syncthreads();

    float acc[64];
    #pragma unroll
    for (int k = 0; k < 64; ++k) acc[k] = 0.f;
    switch (fc) {
        case 0:  zm_accum<0>(h, jc, tid, Qn, V4, Sf, acc); break;
        case 1:  zm_accum<1>(h, jc, tid, Qn, V4, Sf, acc); break;
        case 2:  zm_accum<2>(h, jc, tid, Qn, V4, Sf, acc); break;
        case 3:  zm_accum<3>(h, jc, tid, Qn, V4, Sf, acc); break;
        case 4:  zm_accum<4>(h, jc, tid, Qn, V4, Sf, acc); break;
        case 5:  zm_accum<5>(h, jc, tid, Qn, V4, Sf, acc); break;
        case 6:  zm_accum<6>(h, jc, tid, Qn, V4, Sf, acc); break;
        default: zm_accum<7>(h, jc, tid, Qn, V4, Sf, acc); break;
    }
    #pragma unroll
    for (int off = 32; off; off >>= 1)
        #pragma unroll
        for (int k = 0; k < 64; ++k) acc[k] += __shfl_down(acc[k], off);
    const int lane = tid & 63, wv = tid >> 6;
    if (lane == 0) {
        #pragma unroll
        for (int k = 0; k < 64; ++k) red[wv][k] = acc[k];
    }
    __syncthreads();
    if (tid < 64) {
        int fi = tid >> 2, dd = tid & 3;
        int f = fc * 16 + fi;
        if (f < NF) {
            float s = (red[0][tid] + red[1][tid]) + (red[2][tid] + red[3][tid]);
            int A, B, C, D; f2abcd(f, A, B, C, D);
            s *= (invfact(A) * invfact(B)) * (invfact(C) * invfact(D));
            Mp[((jc * 16 + h) * 128 + f) * 4 + dd] = s;
        }
    }
}

// ---------------------------------------------------------------------------
// Kernel 4: fused AO + output projection + bias + residual.
// Grid (128 tiles of 32 pos, 4 c-blocks of 64 ch) = 512 blocks.
// LDS: M fold (4 jc partials) 32 KB + AO 8.25 KB.
// ---------------------------------------------------------------------------
__global__ __launch_bounds__(256) void outfuse_kernel(
    const float* __restrict__ Kn, const float* __restrict__ Mp,
    const float* __restrict__ Wo, const float* __restrict__ bo,
    const float* __restrict__ X, float* __restrict__ Y)
{
    __shared__ __align__(16) float ML[16 * 128 * 4];   // 32 KB
    __shared__ float AOL[64 * 33];                     // 8.25 KB
    const int tid = threadIdx.x;
    const int it  = blockIdx.x;
    const int cb  = blockIdx.y;
    const int i0  = it * 32;

    {   // fold 4 jc partials -> ML
        const float4* Mp4 = (const float4*)Mp;
        float4* ML4 = (float4*)ML;
        #pragma unroll
        for (int w = 0; w < 8; ++w) {
            int e = tid + w * 256;                     // [0, 2048)
            float4 a = Mp4[e],        b = Mp4[2048 + e];
            float4 c = Mp4[4096 + e], d = Mp4[6144 + e];
            ML4[e] = make_float4((a.x+b.x)+(c.x+d.x), (a.y+b.y)+(c.y+d.y),
                                 (a.z+b.z)+(c.z+d.z), (a.w+b.w)+(c.w+d.w));
        }
    }
    __syncthreads();

    #pragma unroll
    for (int r = 0; r < 2; ++r) {                      // 512 (pos,h) pairs
        int p = tid + r * 256;
        int pos = p & 31, h = p >> 5;
        float4 k = ((const float4*)Kn)[h * SL + i0 + pos];
        BUILD_POWERS(k)
        const float4* Mh = ((const float4*)ML) + h * 128;
        float a0 = 0.f, a1 = 0.f, a2 = 0.f, a3 = 0.f;
        FOR_MONOMIALS({
            float m = (p0[a] * p1[b]) * (p2[c] * p3[d]);
            float4 mm = Mh[f];                         // LDS broadcast
            a0 = fmaf(m, mm.x, a0); a1 = fmaf(m, mm.y, a1);
            a2 = fmaf(m, mm.z, a2); a3 = fmaf(m, mm.w, a3);
        })
        AOL[(h * 4 + 0) * 33 + pos] = a0;
        AOL[(h * 4 + 1) * 33 + pos] = a1;
        AOL[(h * 4 + 2) * 33 + pos] = a2;
        AOL[(h * 4 + 3) * 33 + pos] = a3;
    }
    __syncthreads();

    const int pos = tid & 31, cg = tid >> 5;           // 8 groups of 8 ch
    const int chb = cb * 64 + cg * 8;
    float acc[8];
    #pragma unroll
    for (int u = 0; u < 8; ++u) acc[u] = 0.f;
    #pragma unroll 4
    for (int ob = 0; ob < 16; ++ob) {                  // 4 o's per ob
        float x0 = AOL[(ob * 4 + 0) * 33 + pos];
        float x1 = AOL[(ob * 4 + 1) * 33 + pos];
        float x2 = AOL[(ob * 4 + 2) * 33 + pos];
        float x3 = AOL[(ob * 4 + 3) * 33 + pos];
        #pragma unroll
        for (int u = 0; u < 8; ++u) {
            float4 w4 = ((const float4*)Wo)[(chb + u) * 16 + ob];
            acc[u] = fmaf(w4.x, x0, fmaf(w4.y, x1,
                     fmaf(w4.z, x2, fmaf(w4.w, x3, acc[u]))));
        }
    }
    #pragma unroll
    for (int u = 0; u < 8; ++u) {
        int ch = chb + u;
        Y[ch * SL + i0 + pos] = acc[u] + bo[ch] + X[ch * SL + i0 + pos];
    }
}

// ---------------------------------------------------------------------------
extern "C" void kernel_launch(void* const* d_in, const int* in_sizes, int n_in,
                              void* d_out, int out_size, void* d_ws, size_t ws_size,
                              hipStream_t stream)
{
    const float* X  = (const float*)d_in[0];
    const float* Wq = (const float*)d_in[1];
    const float* bq = (const float*)d_in[2];
    const float* Wk = (const float*)d_in[3];
    const float* bk = (const float*)d_in[4];
    const float* Wv = (const float*)d_in[5];
    const float* bv = (const float*)d_in[6];
    const float* Wo = (const float*)d_in[7];
    const float* bo = (const float*)d_in[8];
    float* Y = (float*)d_out;

    char* w = (char*)d_ws;
    float* Qn = (float*)(w + (0 << 20));   // [16][SL][4]        1 MB
    float* Kn = (float*)(w + (1 << 20));   // [16][SL][4]        1 MB
    float* V4 = (float*)(w + (2 << 20));   // [16][SL][4]        1 MB
    float* Sp = (float*)(w + (3 << 20));   // [4][16][128]       32 KB
    float* Mp = (float*)(w + (3 << 20) + (128 << 10)); // [4][16][128][4] 128 KB

    qkv_kernel<<<dim3(64, 12), 256, 0, stream>>>(X, Wq, bq, Wk, bk, Wv, bv,
                                                 Qn, Kn, V4);
    ssum_kernel<<<dim3(16, 16, 4), 256, 0, stream>>>(Kn, Sp);
    zmv_kernel<<<dim3(8, 16, 4), 256, 0, stream>>>(Qn, V4, Sp, Mp);
    outfuse_kernel<<<dim3(128, 4), 256, 0, stream>>>(Kn, Mp, Wo, bo, X, Y);
}

// Round 13
// 121.849 us; speedup vs baseline: 1.1126x; 1.1126x over previous
//
#include <hip/hip_runtime.h>
#include <math.h>

// MultiheadSelfAttention2D: C=256, AC=64, HEADS=16, HEAD_DIM=4, L=4096.
// Taylor-linearized attention (R5): exp(q.k) ~= T5 on [-1,1], exact rank-126
// monomial factorization:
//   S_f = (1/a!) sum_m k_m^a ;  Z_j = sum_f q_j^a S_f
//   M[f][d] = (1/a!) sum_j q_j^a V[d,j]/Z_j ;  out[d,i] = sum_f k_i^a M[f][d]
//
// R13: REVERT to R10 (best measured: 121.9us). R11 (coop 1-dispatch) was
// neutral; R12 (zvz-into-mmat merge) regressed 13.7us on VGPR pressure +
// 8x redundant Z. R10's structure: 5 dispatches, every kernel >= 2
// blocks/CU, no atomics, no memsets. Remaining wall time is ~42us harness
// poison-fill + ~20us dispatch boundaries + ~30us kernel work.

constexpr int SL = 4096;
constexpr int NF = 126;

__device__ __forceinline__ float invfact(int e) {
    return e < 2 ? 1.f : e == 2 ? 0.5f : e == 3 ? (1.f / 6.f)
         : e == 4 ? (1.f / 24.f) : (1.f / 120.f);
}
__device__ __forceinline__ void f2abcd(int f, int& A, int& B, int& C, int& D) {
    for (int a = 0; a <= 5; ++a)
        for (int b = 0; b <= 5 - a; ++b)
            for (int c = 0; c <= 5 - a - b; ++c)
                for (int d = 0; d <= 5 - a - b - c; ++d)
                    if (f-- == 0) { A = a; B = b; C = c; D = d; return; }
}

#define FOR_MONOMIALS(BODY)                         \
    {                                               \
        int f = 0;                                  \
        _Pragma("unroll")                           \
        for (int a = 0; a <= 5; ++a)                \
        _Pragma("unroll")                           \
        for (int b = 0; b <= 5 - a; ++b)            \
        _Pragma("unroll")                           \
        for (int c = 0; c <= 5 - a - b; ++c)        \
        _Pragma("unroll")                           \
        for (int d = 0; d <= 5 - a - b - c; ++d) {  \
            BODY;                                   \
            ++f;                                    \
        }                                           \
    }

#define BUILD_POWERS(q)                                   \
    float p0[6], p1[6], p2[6], p3[6];                     \
    p0[0] = p1[0] = p2[0] = p3[0] = 1.f;                  \
    _Pragma("unroll")                                     \
    for (int t_ = 1; t_ < 6; ++t_) {                      \
        p0[t_] = p0[t_ - 1] * (q).x; p1[t_] = p1[t_ - 1] * (q).y; \
        p2[t_] = p2[t_ - 1] * (q).z; p3[t_] = p3[t_ - 1] * (q).w; }

// ---------------------------------------------------------------------------
// Kernel 1: QKV projection + L2-norm. Grid (64 l-tiles, 12 row-blocks),
// block 256 (4 waves x 4 rows). No LDS: X streamed via L1/L2.
// ---------------------------------------------------------------------------
__global__ __launch_bounds__(256) void qkv_kernel(
    const float* __restrict__ X,
    const float* __restrict__ Wq, const float* __restrict__ bq,
    const float* __restrict__ Wk, const float* __restrict__ bk,
    const float* __restrict__ Wv, const float* __restrict__ bv,
    float* __restrict__ Qn, float* __restrict__ Kn, float* __restrict__ V4)
{
    const int tid  = threadIdx.x;
    const int lane = tid & 63;
    const int wv   = __builtin_amdgcn_readfirstlane(tid >> 6);
    const int lt   = blockIdx.x;
    const int rb   = blockIdx.y;               // 12 blocks of 16 rows
    const int type = rb >> 2;                  // 0=Q 1=K 2=V, block-uniform
    const int rit  = (rb & 3) * 16 + wv * 4;   // row-in-type, wave-uniform
    const int l    = lt * 64 + lane;

    const float* W = type == 0 ? Wq : type == 1 ? Wk : Wv;
    const float* B = type == 0 ? bq : type == 1 ? bk : bv;
    const float* w0 = W + (rit + 0) * 256;
    const float* w1 = W + (rit + 1) * 256;
    const float* w2 = W + (rit + 2) * 256;
    const float* w3 = W + (rit + 3) * 256;

    float y0 = B[rit + 0], y1 = B[rit + 1], y2 = B[rit + 2], y3 = B[rit + 3];
    const float* Xl = X + l;
    #pragma unroll 8
    for (int c = 0; c < 256; ++c) {
        float x = Xl[c * SL];
        y0 = fmaf(w0[c], x, y0);
        y1 = fmaf(w1[c], x, y1);
        y2 = fmaf(w2[c], x, y2);
        y3 = fmaf(w3[c], x, y3);
    }
    if (type < 2) {
        float n = sqrtf(y0*y0 + y1*y1 + y2*y2 + y3*y3);
        float inv = 1.f / fmaxf(n, 1e-12f);
        y0 *= inv; y1 *= inv; y2 *= inv; y3 *= inv;
    }
    const int h = rit >> 2;
    float* base = type == 0 ? Qn : type == 1 ? Kn : V4;
    ((float4*)base)[h * SL + l] = make_float4(y0, y1, y2, y3);
}

// ---------------------------------------------------------------------------
// Kernel 2: Sp[jc][h][f] = (1/a!) sum over j-chunk(1024) of k^a.
// Grid (16 f-chunks, 16 h, 4 jc) = 1024 blocks.
// ---------------------------------------------------------------------------
template <int FC>
__device__ __forceinline__ void psi_accum(int h, int jc, int tid,
        const float* __restrict__ Kn, float acc[8])
{
    for (int u = 0; u < 4; ++u) {
        int j = jc * 1024 + u * 256 + tid;
        float4 k = ((const float4*)Kn)[h * SL + j];
        BUILD_POWERS(k)
        FOR_MONOMIALS({
            if (f >= FC * 8 && f < FC * 8 + 8)
                acc[f - FC * 8] += (p0[a] * p1[b]) * (p2[c] * p3[d]);
        })
    }
}

__global__ __launch_bounds__(256) void ssum_kernel(
    const float* __restrict__ Kn, float* __restrict__ Sp)
{
    const int tid = threadIdx.x;
    const int fc  = blockIdx.x;
    const int h   = blockIdx.y;
    const int jc  = blockIdx.z;
    float acc[8];
    #pragma unroll
    for (int k = 0; k < 8; ++k) acc[k] = 0.f;
    switch (fc) {
        case 0:  psi_accum<0 >(h, jc, tid, Kn, acc); break;
        case 1:  psi_accum<1 >(h, jc, tid, Kn, acc); break;
        case 2:  psi_accum<2 >(h, jc, tid, Kn, acc); break;
        case 3:  psi_accum<3 >(h, jc, tid, Kn, acc); break;
        case 4:  psi_accum<4 >(h, jc, tid, Kn, acc); break;
        case 5:  psi_accum<5 >(h, jc, tid, Kn, acc); break;
        case 6:  psi_accum<6 >(h, jc, tid, Kn, acc); break;
        case 7:  psi_accum<7 >(h, jc, tid, Kn, acc); break;
        case 8:  psi_accum<8 >(h, jc, tid, Kn, acc); break;
        case 9:  psi_accum<9 >(h, jc, tid, Kn, acc); break;
        case 10: psi_accum<10>(h, jc, tid, Kn, acc); break;
        case 11: psi_accum<11>(h, jc, tid, Kn, acc); break;
        case 12: psi_accum<12>(h, jc, tid, Kn, acc); break;
        case 13: psi_accum<13>(h, jc, tid, Kn, acc); break;
        case 14: psi_accum<14>(h, jc, tid, Kn, acc); break;
        default: psi_accum<15>(h, jc, tid, Kn, acc); break;
    }
    #pragma unroll
    for (int off = 32; off; off >>= 1)
        #pragma unroll
        for (int k = 0; k < 8; ++k) acc[k] += __shfl_down(acc[k], off);
    __shared__ float red[4][8];
    const int lane = tid & 63, wv = tid >> 6;
    if (lane == 0) {
        #pragma unroll
        for (int k = 0; k < 8; ++k) red[wv][k] = acc[k];
    }
    __syncthreads();
    if (tid < 8) {
        int f = fc * 8 + tid;
        if (f < NF) {
            float s = (red[0][tid] + red[1][tid]) + (red[2][tid] + red[3][tid]);
            int A, B, C, D; f2abcd(f, A, B, C, D);
            Sp[(jc * 16 + h) * 128 + f] =
                s * ((invfact(A) * invfact(B)) * (invfact(C) * invfact(D)));
        }
    }
}

// ---------------------------------------------------------------------------
// Kernel 3: fold Sp -> Sf (LDS); Z_j = sum_f q^a Sf; Vz = V/Z.
// Grid (16 j-tiles, 16 h), block 256.
// ---------------------------------------------------------------------------
__global__ __launch_bounds__(256) void zvz_kernel(
    const float* __restrict__ Qn, const float* __restrict__ Sp,
    const float* __restrict__ V4, float* __restrict__ Vz)
{
    __shared__ float Sf[128];
    const int tid = threadIdx.x;
    const int h   = blockIdx.y;
    if (tid < 128) {
        float s = 0.f;
        #pragma unroll
        for (int jc = 0; jc < 4; ++jc) s += Sp[(jc * 16 + h) * 128 + tid];
        Sf[tid] = s;
    }
    __syncthreads();
    const int j = blockIdx.x * 256 + tid;
    float4 q = ((const float4*)Qn)[h * SL + j];
    BUILD_POWERS(q)
    float z = 0.f;
    FOR_MONOMIALS({ z = fmaf((p0[a]*p1[b])*(p2[c]*p3[d]), Sf[f], z); })
    float inv = 1.f / z;
    float4 v = ((const float4*)V4)[h * SL + j];
    ((float4*)Vz)[h * SL + j] = make_float4(v.x*inv, v.y*inv, v.z*inv, v.w*inv);
}

// ---------------------------------------------------------------------------
// Kernel 4: Mp[jc][h][f][d] = (1/a!) sum over j-half of q^a Vz[d,j].
// Grid (16 fc, 16 h, 2 jc) = 512 blocks (2/CU).
// ---------------------------------------------------------------------------
template <int FC>
__device__ __forceinline__ void m_accum(int h, int jc, int tid,
        const float* __restrict__ Qn, const float* __restrict__ Vz,
        float acc[32])
{
    for (int u = 0; u < 8; ++u) {
        int j = jc * 2048 + u * 256 + tid;
        float4 q = ((const float4*)Qn)[h * SL + j];
        float4 v = ((const float4*)Vz)[h * SL + j];
        BUILD_POWERS(q)
        FOR_MONOMIALS({
            if (f >= FC * 8 && f < FC * 8 + 8) {
                const int fi = f - FC * 8;
                float m = (p0[a] * p1[b]) * (p2[c] * p3[d]);
                acc[fi*4+0] = fmaf(m, v.x, acc[fi*4+0]);
                acc[fi*4+1] = fmaf(m, v.y, acc[fi*4+1]);
                acc[fi*4+2] = fmaf(m, v.z, acc[fi*4+2]);
                acc[fi*4+3] = fmaf(m, v.w, acc[fi*4+3]);
            }
        })
    }
}

__global__ __launch_bounds__(256) void mmat_kernel(
    const float* __restrict__ Qn, const float* __restrict__ Vz,
    float* __restrict__ Mp)
{
    const int tid = threadIdx.x;
    const int fc  = blockIdx.x;
    const int h   = blockIdx.y;
    const int jc  = blockIdx.z;
    float acc[32];
    #pragma unroll
    for (int k = 0; k < 32; ++k) acc[k] = 0.f;
    switch (fc) {
        case 0:  m_accum<0 >(h, jc, tid, Qn, Vz, acc); break;
        case 1:  m_accum<1 >(h, jc, tid, Qn, Vz, acc); break;
        case 2:  m_accum<2 >(h, jc, tid, Qn, Vz, acc); break;
        case 3:  m_accum<3 >(h, jc, tid, Qn, Vz, acc); break;
        case 4:  m_accum<4 >(h, jc, tid, Qn, Vz, acc); break;
        case 5:  m_accum<5 >(h, jc, tid, Qn, Vz, acc); break;
        case 6:  m_accum<6 >(h, jc, tid, Qn, Vz, acc); break;
        case 7:  m_accum<7 >(h, jc, tid, Qn, Vz, acc); break;
        case 8:  m_accum<8 >(h, jc, tid, Qn, Vz, acc); break;
        case 9:  m_accum<9 >(h, jc, tid, Qn, Vz, acc); break;
        case 10: m_accum<10>(h, jc, tid, Qn, Vz, acc); break;
        case 11: m_accum<11>(h, jc, tid, Qn, Vz, acc); break;
        case 12: m_accum<12>(h, jc, tid, Qn, Vz, acc); break;
        case 13: m_accum<13>(h, jc, tid, Qn, Vz, acc); break;
        case 14: m_accum<14>(h, jc, tid, Qn, Vz, acc); break;
        default: m_accum<15>(h, jc, tid, Qn, Vz, acc); break;
    }
    #pragma unroll
    for (int off = 32; off; off >>= 1)
        #pragma unroll
        for (int k = 0; k < 32; ++k) acc[k] += __shfl_down(acc[k], off);
    __shared__ float red[4][32];
    const int lane = tid & 63, wv = tid >> 6;
    if (lane == 0) {
        #pragma unroll
        for (int k = 0; k < 32; ++k) red[wv][k] = acc[k];
    }
    __syncthreads();
    if (tid < 32) {
        int fi = tid >> 2, dd = tid & 3;
        int f = fc * 8 + fi;
        if (f < NF) {
            float s = (red[0][tid] + red[1][tid]) + (red[2][tid] + red[3][tid]);
            int A, B, C, D; f2abcd(f, A, B, C, D);
            s *= (invfact(A) * invfact(B)) * (invfact(C) * invfact(D));
            Mp[((jc * 16 + h) * 128 + f) * 4 + dd] = s;
        }
    }
}

// ---------------------------------------------------------------------------
// Kernel 5: fused AO + output projection + bias + residual.
// Grid (128 tiles of 32 pos, 4 c-blocks of 64 ch) = 512 blocks (2/CU,
// 8 waves/CU). LDS: M fold 32 KB + AO 8.25 KB. Phase A: thread -> 2
// (pos,h) pairs, M via LDS broadcast. Phase B: 8 ch/thread, Wo float4.
// ---------------------------------------------------------------------------
__global__ __launch_bounds__(256) void outfuse_kernel(
    const float* __restrict__ Kn, const float* __restrict__ Mp,
    const float* __restrict__ Wo, const float* __restrict__ bo,
    const float* __restrict__ X, float* __restrict__ Y)
{
    __shared__ __align__(16) float ML[16 * 128 * 4];   // 32 KB
    __shared__ float AOL[64 * 33];                     // 8.25 KB
    const int tid = threadIdx.x;
    const int it  = blockIdx.x;
    const int cb  = blockIdx.y;
    const int i0  = it * 32;

    {   // fold Mp (2 jc partials) -> ML  [f=126,127 slots: unused garbage]
        const float4* Mp4 = (const float4*)Mp;
        float4* ML4 = (float4*)ML;
        #pragma unroll
        for (int w = 0; w < 8; ++w) {
            int e = tid + w * 256;                     // [0, 2048)
            float4 a = Mp4[e], b = Mp4[2048 + e];
            ML4[e] = make_float4(a.x+b.x, a.y+b.y, a.z+b.z, a.w+b.w);
        }
    }
    __syncthreads();

    #pragma unroll
    for (int r = 0; r < 2; ++r) {                      // 512 (pos,h) pairs
        int p = tid + r * 256;
        int pos = p & 31, h = p >> 5;
        float4 k = ((const float4*)Kn)[h * SL + i0 + pos];
        BUILD_POWERS(k)
        const float4* Mh = ((const float4*)ML) + h * 128;
        float a0 = 0.f, a1 = 0.f, a2 = 0.f, a3 = 0.f;
        FOR_MONOMIALS({
            float m = (p0[a] * p1[b]) * (p2[c] * p3[d]);
            float4 mm = Mh[f];                         // LDS broadcast
            a0 = fmaf(m, mm.x, a0); a1 = fmaf(m, mm.y, a1);
            a2 = fmaf(m, mm.z, a2); a3 = fmaf(m, mm.w, a3);
        })
        AOL[(h * 4 + 0) * 33 + pos] = a0;
        AOL[(h * 4 + 1) * 33 + pos] = a1;
        AOL[(h * 4 + 2) * 33 + pos] = a2;
        AOL[(h * 4 + 3) * 33 + pos] = a3;
    }
    __syncthreads();

    const int pos = tid & 31, cg = tid >> 5;           // 8 groups of 8 ch
    const int chb = cb * 64 + cg * 8;
    float acc[8];
    #pragma unroll
    for (int u = 0; u < 8; ++u) acc[u] = 0.f;
    #pragma unroll 4
    for (int ob = 0; ob < 16; ++ob) {                  // 4 o's per ob
        float x0 = AOL[(ob * 4 + 0) * 33 + pos];
        float x1 = AOL[(ob * 4 + 1) * 33 + pos];
        float x2 = AOL[(ob * 4 + 2) * 33 + pos];
        float x3 = AOL[(ob * 4 + 3) * 33 + pos];
        #pragma unroll
        for (int u = 0; u < 8; ++u) {
            float4 w4 = ((const float4*)Wo)[(chb + u) * 16 + ob];
            acc[u] = fmaf(w4.x, x0, fmaf(w4.y, x1,
                     fmaf(w4.z, x2, fmaf(w4.w, x3, acc[u]))));
        }
    }
    #pragma unroll
    for (int u = 0; u < 8; ++u) {
        int ch = chb + u;
        Y[ch * SL + i0 + pos] = acc[u] + bo[ch] + X[ch * SL + i0 + pos];
    }
}

// ---------------------------------------------------------------------------
extern "C" void kernel_launch(void* const* d_in, const int* in_sizes, int n_in,
                              void* d_out, int out_size, void* d_ws, size_t ws_size,
                              hipStream_t stream)
{
    const float* X  = (const float*)d_in[0];
    const float* Wq = (const float*)d_in[1];
    const float* bq = (const float*)d_in[2];
    const float* Wk = (const float*)d_in[3];
    const float* bk = (const float*)d_in[4];
    const float* Wv = (const float*)d_in[5];
    const float* bv = (const float*)d_in[6];
    const float* Wo = (const float*)d_in[7];
    const float* bo = (const float*)d_in[8];
    float* Y = (float*)d_out;

    char* w = (char*)d_ws;
    float* Qn = (float*)(w + (0 << 20));   // [16][SL][4]        1 MB
    float* Kn = (float*)(w + (1 << 20));   // [16][SL][4]        1 MB
    float* V4 = (float*)(w + (2 << 20));   // [16][SL][4]        1 MB
    float* Vz = (float*)(w + (3 << 20));   // [16][SL][4]        1 MB
    float* Sp = (float*)(w + (4 << 20));   // [4][16][128]       32 KB
    float* Mp = (float*)(w + (4 << 20) + (128 << 10)); // [2][16][128][4] 64 KB

    qkv_kernel<<<dim3(64, 12), 256, 0, stream>>>(X, Wq, bq, Wk, bk, Wv, bv,
                                                 Qn, Kn, V4);
    ssum_kernel<<<dim3(16, 16, 4), 256, 0, stream>>>(Kn, Sp);
    zvz_kernel<<<dim3(16, 16), 256, 0, stream>>>(Qn, Sp, V4, Vz);
    mmat_kernel<<<dim3(16, 16, 2), 256, 0, stream>>>(Qn, Vz, Mp);
    outfuse_kernel<<<dim3(128, 4), 256, 0, stream>>>(Kn, Mp, Wo, bo, X, Y);
}